// Round 5
// baseline (446.814 us; speedup 1.0000x reference)
//
#include <hip/hip_runtime.h>

typedef unsigned short u16;
typedef unsigned int u32;
typedef __bf16 bf16x8 __attribute__((ext_vector_type(8)));
typedef short s16x4 __attribute__((ext_vector_type(4)));
typedef float f32x4 __attribute__((ext_vector_type(4)));

#define BB   4
#define TT   1024
#define CDIM 2048
#define NH   16
#define NKV  4
#define HDIM 128

__device__ __forceinline__ float b2f(u16 u) {
    union { u32 i; float f; } x; x.i = ((u32)u) << 16; return x.f;
}
__device__ __forceinline__ u16 f2b(float f) {
    union { float f; u32 i; } x; x.f = f;
    u32 r = (x.i + 0x7fffu + ((x.i >> 16) & 1u)) >> 16;
    return (u16)r;
}
__device__ __forceinline__ void async16(const void* g, void* l) {
    __builtin_amdgcn_global_load_lds((const __attribute__((address_space(1))) void*)g,
                                     (__attribute__((address_space(3))) void*)l, 16, 0, 0);
}

// ---------------------------------------------------------------------------
// Dtype probe — sample EVEN u16 indices (low mantissa halves of fp32).
// ---------------------------------------------------------------------------
__global__ void detect_k(const u16* __restrict__ x, u32* __restrict__ flag) {
    __shared__ int cnt;
    if (threadIdx.x == 0) cnt = 0;
    __syncthreads();
    int bad = 0;
#pragma unroll
    for (int i = 0; i < 4; i++) {
        u16 v = x[(threadIdx.x * 4 + i) * 2];    // EVEN index
        int e = (v >> 7) & 0xFF;
        if (v != 0 && (e < 90 || e > 160)) bad++;
    }
    atomicAdd(&cnt, bad);
    __syncthreads();
    if (threadIdx.x == 0) *flag = (cnt > 100) ? 1u : 0u;
}

// Convert-or-copy to bf16, 4 elements per thread. n multiple of 1024.
__global__ __launch_bounds__(256) void conv_k(const void* __restrict__ src,
                                              u16* __restrict__ dst,
                                              const u32* __restrict__ flag, int n) {
    int i = blockIdx.x * 256 + threadIdx.x;
    if (i * 4 >= n) return;
    union { u16 u[4]; ushort4 v; } o;
    if (*flag) {
        float4 f = ((const float4*)src)[i];
        o.u[0] = f2b(f.x); o.u[1] = f2b(f.y); o.u[2] = f2b(f.z); o.u[3] = f2b(f.w);
    } else {
        o.v = ((const ushort4*)src)[i];
    }
    ((ushort4*)dst)[i] = o.v;
}

// ---------------------------------------------------------------------------
// Tiled transpose with dtype-flexible load: WT[c][r] = bf16(W[r][c]).
// ---------------------------------------------------------------------------
__global__ __launch_bounds__(256) void transpose_k(const void* __restrict__ W,
                                                   u16* __restrict__ WT,
                                                   int rows, int cols,
                                                   const u32* __restrict__ flag) {
    __shared__ alignas(16) u16 tile[64 * 65];
    const bool f32m = (*flag != 0);
    const int r0 = blockIdx.y * 64, c0 = blockIdx.x * 64;
#pragma unroll
    for (int i = 0; i < 16; i++) {
        int c = threadIdx.x + i * 256;
        int rr = c >> 6, cc = c & 63;
        long idx = (long)(r0 + rr) * cols + c0 + cc;
        tile[rr * 65 + cc] = f32m ? f2b(((const float*)W)[idx]) : ((const u16*)W)[idx];
    }
    __syncthreads();
#pragma unroll
    for (int i = 0; i < 16; i++) {
        int c = threadIdx.x + i * 256;
        int rr = c >> 6, cc = c & 63;
        WT[(long)(c0 + rr) * rows + r0 + cc] = tile[cc * 65 + rr];
    }
}

// ---------------------------------------------------------------------------
// m97-style bf16 GEMM: C[m][n] = sum_k A[m][k] * Bt[n][k].
// ---------------------------------------------------------------------------
__global__ __launch_bounds__(256) void gemm_bt(const u16* __restrict__ A,
                                               const u16* __restrict__ Bt,
                                               void* __restrict__ C,
                                               int M, int N, int Kd,
                                               const u32* __restrict__ flag) {
    __shared__ alignas(16) u16 As[128 * 32];
    __shared__ alignas(16) u16 Bs[128 * 32];
    const int tid = threadIdx.x;
    const int w = tid >> 6, lane = tid & 63;
    const int wm = w >> 1, wn = w & 1;
    const int l16 = lane & 15, quad = lane >> 4;
    const int bm = blockIdx.y, bn = blockIdx.x;
    const long arow0 = (long)bm * 128;
    const long brow0 = (long)bn * 128;
    const int srow = lane >> 2;
    const int schunk = lane & 3;

    f32x4 acc[4][4];
#pragma unroll
    for (int i = 0; i < 4; i++)
#pragma unroll
        for (int j = 0; j < 4; j++) acc[i][j] = {0.f, 0.f, 0.f, 0.f};

    for (int k0 = 0; k0 < Kd; k0 += 32) {
        __syncthreads();
#pragma unroll
        for (int j = 0; j < 2; j++) {
            int r0 = w * 32 + j * 16;
            const u16* gA = A + (arow0 + r0 + srow) * Kd + k0 + schunk * 8;
            async16(gA, &As[r0 * 32]);
            const u16* gB = Bt + (brow0 + r0 + srow) * Kd + k0 + schunk * 8;
            async16(gB, &Bs[r0 * 32]);
        }
        __syncthreads();
        bf16x8 af[4], bfr[4];
#pragma unroll
        for (int mt = 0; mt < 4; mt++)
            af[mt] = *(const bf16x8*)&As[(wm * 64 + mt * 16 + l16) * 32 + quad * 8];
#pragma unroll
        for (int nt = 0; nt < 4; nt++)
            bfr[nt] = *(const bf16x8*)&Bs[(wn * 64 + nt * 16 + l16) * 32 + quad * 8];
#pragma unroll
        for (int mt = 0; mt < 4; mt++)
#pragma unroll
            for (int nt = 0; nt < 4; nt++)
                acc[mt][nt] = __builtin_amdgcn_mfma_f32_16x16x32_bf16(
                    af[mt], bfr[nt], acc[mt][nt], 0, 0, 0);
    }
    const bool f32m = (flag != nullptr) && (*flag != 0);
#pragma unroll
    for (int mt = 0; mt < 4; mt++) {
#pragma unroll
        for (int nt = 0; nt < 4; nt++) {
            int col = bn * 128 + wn * 64 + nt * 16 + l16;
#pragma unroll
            for (int r = 0; r < 4; r++) {
                long row = bm * 128 + wm * 64 + mt * 16 + quad * 4 + r;
                if (f32m) ((float*)C)[row * N + col] = acc[mt][nt][r];
                else      ((u16*)C)[row * N + col] = f2b(acc[mt][nt][r]);
            }
        }
    }
}

// ---------------------------------------------------------------------------
// RoPE on Q: QKVraw (B*T, 3072) cols [h*128..] -> Q (B,H,T,HD)
// ---------------------------------------------------------------------------
__global__ __launch_bounds__(256) void rope_q_kernel(const u16* __restrict__ QKVraw,
                                                     const u16* __restrict__ cs,
                                                     const u16* __restrict__ sn,
                                                     u16* __restrict__ Q) {
    int idx = blockIdx.x * 256 + threadIdx.x;
    int d = idx & 63;
    int t = (idx >> 6) & (TT - 1);
    int bh = idx >> 16;
    long src = ((long)((bh >> 4) * TT + t)) * 3072 + (bh & 15) * HDIM;
    float u1 = b2f(QKVraw[src + d]), u2 = b2f(QKVraw[src + d + 64]);
    float c = b2f(cs[t * 64 + d]), s = b2f(sn[t * 64 + d]);
    long dst = ((long)bh * TT + t) * HDIM;
    Q[dst + d] = f2b(u1 * c - u2 * s);
    Q[dst + d + 64] = f2b(u1 * s + u2 * c);
}

// RoPE on K: QKVraw cols [2048 + kvh*128..] -> K (B,KVH,T,HD)
__global__ __launch_bounds__(256) void rope_k_kernel(const u16* __restrict__ QKVraw,
                                                     const u16* __restrict__ cs,
                                                     const u16* __restrict__ sn,
                                                     u16* __restrict__ K) {
    int idx = blockIdx.x * 256 + threadIdx.x;
    int d = idx & 63;
    int t = (idx >> 6) & (TT - 1);
    int bk = idx >> 16;
    long src = ((long)((bk >> 2) * TT + t)) * 3072 + 2048 + (bk & 3) * HDIM;
    float u1 = b2f(QKVraw[src + d]), u2 = b2f(QKVraw[src + d + 64]);
    float c = b2f(cs[t * 64 + d]), s = b2f(sn[t * 64 + d]);
    long dst = ((long)bk * TT + t) * HDIM;
    K[dst + d] = f2b(u1 * c - u2 * s);
    K[dst + d + 64] = f2b(u1 * s + u2 * c);
}

// V rearrange: QKVraw cols [2560 + kvh*128 + d] -> Vt (B,KVH,HD,T)
__global__ __launch_bounds__(256) void vt_kernel(const u16* __restrict__ QKVraw,
                                                 u16* __restrict__ Vt) {
    int idx = blockIdx.x * 256 + threadIdx.x;
    int t = idx & (TT - 1);
    int d = (idx >> 10) & (HDIM - 1);
    int bk = idx >> 17;
    Vt[idx] = QKVraw[((long)(bk >> 2) * TT + t) * 3072 + 2560 + (bk & 3) * HDIM + d];
}

// ---------------------------------------------------------------------------
// Flash attention v3 — S^T formulation + register-direct PV.
// Key trick: mfma_16x16x16 B-fragment layout (k = quad*4+j) equals the S^T
// C-layout k-distribution (k = nt*16+quad*4+r), so softmaxed P feeds the PV
// MFMA directly from registers — no LDS transport, LDS 48KB -> 3 blocks/CU.
// ---------------------------------------------------------------------------
#define HAVE_MFMA16 __has_builtin(__builtin_amdgcn_mfma_f32_16x16x16bf16_1k)

__global__ __launch_bounds__(256) void attn_kernel(const u16* __restrict__ Q,
                                                   const u16* __restrict__ Kr,
                                                   const u16* __restrict__ Vt,
                                                   u16* __restrict__ O) {
    __shared__ alignas(16) u16 Qs[64 * 128];   // [q][d], 8-elem chunk ^= row&7 (keep bit3)
    __shared__ alignas(16) u16 Ks[64 * 128];   // [t][d], same swizzle
    __shared__ alignas(16) u16 Vts[128 * 64];  // [d][t], chunk ^= row&7
#if !HAVE_MFMA16
    __shared__ alignas(16) u16 Ps[64 * 88];    // fallback transport
#endif

    const int tid = threadIdx.x, w = tid >> 6, lane = tid & 63;
    const int l16 = lane & 15, quad = lane >> 4;
    const int bid = blockIdx.x;
    const int qt = 15 - (bid & 15);          // heavy tiles first
    const int bh = bid >> 4;
    const int b = bh >> 4, h = bh & 15;
    const int kvh = h >> 2;
    const long qrow0 = (long)bh * TT + qt * 64;
    const long krow0 = (long)(b * NKV + kvh) * TT;
    const long vbase = ((long)(b * NKV + kvh) * HDIM) * TT;

#pragma unroll
    for (int i = 0; i < 4; i++) {
        int slot0 = (w * 4 + i) * 64;
        int slot = slot0 + lane;
        int row = slot >> 4, cp = slot & 15;
        int cg = (cp & 8) | ((cp ^ row) & 7);
        async16(Q + (qrow0 + row) * HDIM + cg * 8, &Qs[slot0 * 8]);
    }

    f32x4 o[8];
#pragma unroll
    for (int i = 0; i < 8; i++) o[i] = {0.f, 0.f, 0.f, 0.f};
    float m_i = -1.0e30f, l_i = 0.f;
    const int qg = qt * 64 + w * 16 + l16;
    // exp2-domain: fold 1/sqrt(128) * log2(e) into one scale
    const float scale2 = 0.08838834764831845f * 1.4426950408889634f;

    for (int kt = 0; kt <= qt; kt++) {
        __syncthreads();
#pragma unroll
        for (int i = 0; i < 4; i++) {
            int slot0 = (w * 4 + i) * 64;
            int slot = slot0 + lane;
            int row = slot >> 4, cp = slot & 15;
            int cg = (cp & 8) | ((cp ^ row) & 7);
            async16(Kr + (krow0 + kt * 64 + row) * HDIM + cg * 8, &Ks[slot0 * 8]);
        }
#pragma unroll
        for (int i = 0; i < 4; i++) {
            int slot0 = (w * 4 + i) * 64;
            int slot = slot0 + lane;
            int row = slot >> 3, cp = slot & 7;
            int cg = cp ^ (row & 7);
            async16(Vt + vbase + (long)row * TT + kt * 64 + cg * 8, &Vts[slot0 * 8]);
        }
        __syncthreads();

        // S^T[k][q] = sum_d K[k][d] * Q[q][d]
        f32x4 s[4];
#pragma unroll
        for (int nt = 0; nt < 4; nt++) s[nt] = {0.f, 0.f, 0.f, 0.f};
#pragma unroll
        for (int ds = 0; ds < 4; ds++) {
            int Rq = w * 16 + l16;
            int c = ds * 4 + quad;
            bf16x8 bq = *(const bf16x8*)&Qs[Rq * 128 + ((c & 8) | ((c ^ Rq) & 7)) * 8];
#pragma unroll
            for (int nt = 0; nt < 4; nt++) {
                int Rk = nt * 16 + l16;
                bf16x8 ak = *(const bf16x8*)&Ks[Rk * 128 + ((c & 8) | ((c ^ Rk) & 7)) * 8];
                s[nt] = __builtin_amdgcn_mfma_f32_16x16x32_bf16(ak, bq, s[nt], 0, 0, 0);
            }
        }

        // online softmax (exp2 domain), per-lane column + cross-quad reduce
        float p[4][4];
        float mx = -1.0e30f;
        if (kt == qt) {
#pragma unroll
            for (int nt = 0; nt < 4; nt++)
#pragma unroll
                for (int r = 0; r < 4; r++) {
                    int kcol = kt * 64 + nt * 16 + quad * 4 + r;
                    float v = (kcol <= qg) ? (float)s[nt][r] * scale2 : -1.0e30f;
                    p[nt][r] = v;
                    mx = fmaxf(mx, v);
                }
        } else {
#pragma unroll
            for (int nt = 0; nt < 4; nt++)
#pragma unroll
                for (int r = 0; r < 4; r++) {
                    float v = (float)s[nt][r] * scale2;
                    p[nt][r] = v;
                    mx = fmaxf(mx, v);
                }
        }
        mx = fmaxf(mx, __shfl_xor(mx, 16));
        mx = fmaxf(mx, __shfl_xor(mx, 32));
        float mnew = fmaxf(m_i, mx);
        float alpha = exp2f(m_i - mnew);
        float rs = 0.f;
#pragma unroll
        for (int nt = 0; nt < 4; nt++)
#pragma unroll
            for (int r = 0; r < 4; r++) {
                float e = exp2f(p[nt][r] - mnew);
                p[nt][r] = e;
                rs += e;
            }
        rs += __shfl_xor(rs, 16);
        rs += __shfl_xor(rs, 32);
        l_i = l_i * alpha + rs;
        m_i = mnew;

        // rescale O (alpha lane-uniform)
#pragma unroll
        for (int n8 = 0; n8 < 8; n8++)
#pragma unroll
            for (int r = 0; r < 4; r++) o[n8][r] *= alpha;

#if HAVE_MFMA16
        // O^T[d][q] += V^T[d][k] * P[q][k] — P direct from registers:
        // x16 B-frag k=quad*4+j matches S^T C-layout k=nt*16+quad*4+r.
#pragma unroll
        for (int nt = 0; nt < 4; nt++) {
            s16x4 bp;
            bp[0] = (short)f2b(p[nt][0]);
            bp[1] = (short)f2b(p[nt][1]);
            bp[2] = (short)f2b(p[nt][2]);
            bp[3] = (short)f2b(p[nt][3]);
            int c = nt * 2 + (quad >> 1);
#pragma unroll
            for (int n8 = 0; n8 < 8; n8++) {
                int Rv = n8 * 16 + l16;
                s16x4 av = *(const s16x4*)&Vts[Rv * 64 + ((c ^ (Rv & 7)) << 3) + (quad & 1) * 4];
                o[n8] = __builtin_amdgcn_mfma_f32_16x16x16bf16_1k(av, bp, o[n8], 0, 0, 0);
            }
        }
#else
        // fallback: P via LDS (packed u32 write, b128 read, same-wave)
        {
            u32* Psw = (u32*)Ps;
            int pb = (w * 16 + l16) * 44 + quad * 2;
#pragma unroll
            for (int nt = 0; nt < 4; nt++) {
                u32 lo = (u32)f2b(p[nt][0]) | ((u32)f2b(p[nt][1]) << 16);
                u32 hi = (u32)f2b(p[nt][2]) | ((u32)f2b(p[nt][3]) << 16);
                Psw[pb + nt * 8]     = lo;
                Psw[pb + nt * 8 + 1] = hi;
            }
            asm volatile("s_waitcnt lgkmcnt(0)" ::: "memory");
#pragma unroll
            for (int ks = 0; ks < 2; ks++) {
                bf16x8 bp = *(const bf16x8*)&Ps[(w * 16 + l16) * 88 + ks * 32 + quad * 8];
#pragma unroll
                for (int n8 = 0; n8 < 8; n8++) {
                    int Rv = n8 * 16 + l16;
                    int c = ks * 4 + quad;
                    bf16x8 av = *(const bf16x8*)&Vts[Rv * 64 + (c ^ (Rv & 7)) * 8];
                    o[n8] = __builtin_amdgcn_mfma_f32_16x16x32_bf16(av, bp, o[n8], 0, 0, 0);
                }
            }
        }
#endif
    }

    // epilogue: normalize, pack 4 bf16, store
    float inv = 1.0f / l_i;
    long obase = ((long)(b * TT + qg)) * CDIM + h * HDIM;
#pragma unroll
    for (int n8 = 0; n8 < 8; n8++) {
        ushort4 st;
        st.x = f2b(o[n8][0] * inv);
        st.y = f2b(o[n8][1] * inv);
        st.z = f2b(o[n8][2] * inv);
        st.w = f2b(o[n8][3] * inv);
        *(ushort4*)&O[obase + n8 * 16 + quad * 4] = st;
    }
}

// ---------------------------------------------------------------------------
extern "C" void kernel_launch(void* const* d_in, const int* in_sizes, int n_in,
                              void* d_out, int out_size, void* d_ws, size_t ws_size,
                              hipStream_t stream) {
    const void* x   = d_in[0];
    const void* Wq  = d_in[1];
    const void* Wkv = d_in[2];
    const void* Wo  = d_in[3];
    const void* cs  = d_in[4];
    const void* sn  = d_in[5];

    char* ws = (char*)d_ws;
    const size_t NEED = 105119748;
    if (ws_size < NEED) return;

    u16* WqkvT = (u16*)(ws + 0);          // 3072x2048 (WqT 2048 rows ++ WkvT 1024 rows)
    u16* WoT   = (u16*)(ws + 12582912);   // 2048x2048
    u16* QKVraw= (u16*)(ws + 20971520);   // 4096x3072
    u16* Qr    = (u16*)(ws + 46137344);   // (B,H,T,HD)
    u16* Kr    = (u16*)(ws + 62914560);   // (B,KVH,T,HD)
    u16* Vt    = (u16*)(ws + 67108864);   // (B,KVH,HD,T)
    u16* ATT   = (u16*)(ws + 71303168);   // 4096x2048
    u16* xb    = (u16*)(ws + 88080384);   // 4096x2048 bf16 x
    u16* csb   = (u16*)(ws + 104857600);  // 1024x64
    u16* snb   = (u16*)(ws + 104988672);  // 1024x64
    u32* flag  = (u32*)(ws + 105119744);

    detect_k<<<1, 256, 0, stream>>>((const u16*)x, flag);

    conv_k<<<8192, 256, 0, stream>>>(x, xb, flag, 8388608);
    conv_k<<<64, 256, 0, stream>>>(cs, csb, flag, 65536);
    conv_k<<<64, 256, 0, stream>>>(sn, snb, flag, 65536);

    transpose_k<<<dim3(32, 32), 256, 0, stream>>>(Wq, WqkvT, 2048, 2048, flag);
    transpose_k<<<dim3(16, 32), 256, 0, stream>>>(Wkv, WqkvT + (long)2048 * 2048, 2048, 1024, flag);
    transpose_k<<<dim3(32, 32), 256, 0, stream>>>(Wo, WoT, 2048, 2048, flag);

    gemm_bt<<<dim3(24, 32), 256, 0, stream>>>(xb, WqkvT, QKVraw, 4096, 3072, 2048, nullptr);

    rope_q_kernel<<<16384, 256, 0, stream>>>(QKVraw, csb, snb, Qr);
    rope_k_kernel<<<4096, 256, 0, stream>>>(QKVraw, csb, snb, Kr);
    vt_kernel<<<8192, 256, 0, stream>>>(QKVraw, Vt);

    attn_kernel<<<1024, 256, 0, stream>>>(Qr, Kr, Vt, ATT);

    gemm_bt<<<dim3(16, 32), 256, 0, stream>>>(ATT, WoT, d_out, 4096, 2048, 2048, flag);
}

// Round 6
// 361.888 us; speedup vs baseline: 1.2347x; 1.2347x over previous
//
#include <hip/hip_runtime.h>

typedef unsigned short u16;
typedef unsigned int u32;
typedef __bf16 bf16x8 __attribute__((ext_vector_type(8)));
typedef float f32x4 __attribute__((ext_vector_type(4)));

#define BB   4
#define TT   1024
#define CDIM 2048
#define NH   16
#define NKV  4
#define HDIM 128

__device__ __forceinline__ float b2f(u16 u) {
    union { u32 i; float f; } x; x.i = ((u32)u) << 16; return x.f;
}
__device__ __forceinline__ u16 f2b(float f) {
    union { float f; u32 i; } x; x.f = f;
    u32 r = (x.i + 0x7fffu + ((x.i >> 16) & 1u)) >> 16;
    return (u16)r;
}
__device__ __forceinline__ void async16(const void* g, void* l) {
    __builtin_amdgcn_global_load_lds((const __attribute__((address_space(1))) void*)g,
                                     (__attribute__((address_space(3))) void*)l, 16, 0, 0);
}

// ---------------------------------------------------------------------------
// Dtype probe — sample EVEN u16 indices (low mantissa halves of fp32).
// ---------------------------------------------------------------------------
__global__ void detect_k(const u16* __restrict__ x, u32* __restrict__ flag) {
    __shared__ int cnt;
    if (threadIdx.x == 0) cnt = 0;
    __syncthreads();
    int bad = 0;
#pragma unroll
    for (int i = 0; i < 4; i++) {
        u16 v = x[(threadIdx.x * 4 + i) * 2];    // EVEN index
        int e = (v >> 7) & 0xFF;
        if (v != 0 && (e < 90 || e > 160)) bad++;
    }
    atomicAdd(&cnt, bad);
    __syncthreads();
    if (threadIdx.x == 0) *flag = (cnt > 100) ? 1u : 0u;
}

// Convert-or-copy x to bf16, 4 elements per thread.
__global__ __launch_bounds__(256) void conv_k(const void* __restrict__ src,
                                              u16* __restrict__ dst,
                                              const u32* __restrict__ flag, int n) {
    int i = blockIdx.x * 256 + threadIdx.x;
    if (i * 4 >= n) return;
    union { u16 u[4]; ushort4 v; } o;
    if (*flag) {
        float4 f = ((const float4*)src)[i];
        o.u[0] = f2b(f.x); o.u[1] = f2b(f.y); o.u[2] = f2b(f.z); o.u[3] = f2b(f.w);
    } else {
        o.v = ((const ushort4*)src)[i];
    }
    ((ushort4*)dst)[i] = o.v;
}

// cos+sin conversion in one dispatch (64 blocks each).
__global__ __launch_bounds__(256) void conv2_k(const void* __restrict__ cs,
                                               const void* __restrict__ sn,
                                               u16* __restrict__ csb,
                                               u16* __restrict__ snb,
                                               const u32* __restrict__ flag) {
    int bid = blockIdx.x;
    const void* src = (bid < 64) ? cs : sn;
    u16* dst = (bid < 64) ? csb : snb;
    int i = (bid & 63) * 256 + threadIdx.x;
    union { u16 u[4]; ushort4 v; } o;
    if (*flag) {
        float4 f = ((const float4*)src)[i];
        o.u[0] = f2b(f.x); o.u[1] = f2b(f.y); o.u[2] = f2b(f.z); o.u[3] = f2b(f.w);
    } else {
        o.v = ((const ushort4*)src)[i];
    }
    ((ushort4*)dst)[i] = o.v;
}

// ---------------------------------------------------------------------------
// All three weight transposes in one dispatch. WT[c][r] = bf16(W[r][c]).
// ---------------------------------------------------------------------------
__global__ __launch_bounds__(256) void transpose_all_k(const void* __restrict__ Wq,
                                                       const void* __restrict__ Wkv,
                                                       const void* __restrict__ Wo,
                                                       u16* __restrict__ WqkvT,
                                                       u16* __restrict__ WoT,
                                                       const u32* __restrict__ flag) {
    __shared__ alignas(16) u16 tile[64 * 65];
    const bool f32m = (*flag != 0);
    int bid = blockIdx.x;
    const void* W; u16* WT; int rows, cols, bx, by;
    if (bid < 1024)      { W = Wq;  WT = WqkvT;                    rows = 2048; cols = 2048; bx = bid & 31;  by = bid >> 5; }
    else if (bid < 1536) { int l = bid - 1024; W = Wkv; WT = WqkvT + (long)2048 * 2048; rows = 2048; cols = 1024; bx = l & 15; by = l >> 4; }
    else                 { int l = bid - 1536; W = Wo;  WT = WoT;  rows = 2048; cols = 2048; bx = l & 31;   by = l >> 5; }
    const int r0 = by * 64, c0 = bx * 64;
#pragma unroll
    for (int i = 0; i < 16; i++) {
        int c = threadIdx.x + i * 256;
        int rr = c >> 6, cc = c & 63;
        long idx = (long)(r0 + rr) * cols + c0 + cc;
        tile[rr * 65 + cc] = f32m ? f2b(((const float*)W)[idx]) : ((const u16*)W)[idx];
    }
    __syncthreads();
#pragma unroll
    for (int i = 0; i < 16; i++) {
        int c = threadIdx.x + i * 256;
        int rr = c >> 6, cc = c & 63;
        WT[(long)(c0 + rr) * rows + r0 + cc] = tile[cc * 65 + rr];
    }
}

// ---------------------------------------------------------------------------
// m97-style bf16 GEMM: C[m][n] = sum_k A[m][k] * Bt[n][k].
// ---------------------------------------------------------------------------
__global__ __launch_bounds__(256) void gemm_bt(const u16* __restrict__ A,
                                               const u16* __restrict__ Bt,
                                               void* __restrict__ C,
                                               int M, int N, int Kd,
                                               const u32* __restrict__ flag) {
    __shared__ alignas(16) u16 As[128 * 32];
    __shared__ alignas(16) u16 Bs[128 * 32];
    const int tid = threadIdx.x;
    const int w = tid >> 6, lane = tid & 63;
    const int wm = w >> 1, wn = w & 1;
    const int l16 = lane & 15, quad = lane >> 4;
    const int bm = blockIdx.y, bn = blockIdx.x;
    const long arow0 = (long)bm * 128;
    const long brow0 = (long)bn * 128;
    const int srow = lane >> 2;
    const int schunk = lane & 3;

    f32x4 acc[4][4];
#pragma unroll
    for (int i = 0; i < 4; i++)
#pragma unroll
        for (int j = 0; j < 4; j++) acc[i][j] = {0.f, 0.f, 0.f, 0.f};

    for (int k0 = 0; k0 < Kd; k0 += 32) {
        __syncthreads();
#pragma unroll
        for (int j = 0; j < 2; j++) {
            int r0 = w * 32 + j * 16;
            const u16* gA = A + (arow0 + r0 + srow) * Kd + k0 + schunk * 8;
            async16(gA, &As[r0 * 32]);
            const u16* gB = Bt + (brow0 + r0 + srow) * Kd + k0 + schunk * 8;
            async16(gB, &Bs[r0 * 32]);
        }
        __syncthreads();
        bf16x8 af[4], bfr[4];
#pragma unroll
        for (int mt = 0; mt < 4; mt++)
            af[mt] = *(const bf16x8*)&As[(wm * 64 + mt * 16 + l16) * 32 + quad * 8];
#pragma unroll
        for (int nt = 0; nt < 4; nt++)
            bfr[nt] = *(const bf16x8*)&Bs[(wn * 64 + nt * 16 + l16) * 32 + quad * 8];
#pragma unroll
        for (int mt = 0; mt < 4; mt++)
#pragma unroll
            for (int nt = 0; nt < 4; nt++)
                acc[mt][nt] = __builtin_amdgcn_mfma_f32_16x16x32_bf16(
                    af[mt], bfr[nt], acc[mt][nt], 0, 0, 0);
    }
    const bool f32m = (flag != nullptr) && (*flag != 0);
#pragma unroll
    for (int mt = 0; mt < 4; mt++) {
#pragma unroll
        for (int nt = 0; nt < 4; nt++) {
            int col = bn * 128 + wn * 64 + nt * 16 + l16;
#pragma unroll
            for (int r = 0; r < 4; r++) {
                long row = bm * 128 + wm * 64 + mt * 16 + quad * 4 + r;
                if (f32m) ((float*)C)[row * N + col] = acc[mt][nt][r];
                else      ((u16*)C)[row * N + col] = f2b(acc[mt][nt][r]);
            }
        }
    }
}

// ---------------------------------------------------------------------------
// RoPE(Q), RoPE(K), V-transpose in ONE dispatch, split by block ranges.
// QKVraw (B*T, 3072): [0,2048)=Q heads, [2048,2560)=K, [2560,3072)=V.
// ---------------------------------------------------------------------------
__global__ __launch_bounds__(256) void prep_k(const u16* __restrict__ QKVraw,
                                              const u16* __restrict__ cs,
                                              const u16* __restrict__ sn,
                                              u16* __restrict__ Qr,
                                              u16* __restrict__ Kr,
                                              u16* __restrict__ Vt) {
    int bid = blockIdx.x;
    if (bid < 16384) {                       // RoPE Q -> (B,H,T,HD)
        int idx = bid * 256 + threadIdx.x;
        int d = idx & 63;
        int t = (idx >> 6) & (TT - 1);
        int bh = idx >> 16;
        long src = ((long)((bh >> 4) * TT + t)) * 3072 + (bh & 15) * HDIM;
        float u1 = b2f(QKVraw[src + d]), u2 = b2f(QKVraw[src + d + 64]);
        float c = b2f(cs[t * 64 + d]), s = b2f(sn[t * 64 + d]);
        long dst = ((long)bh * TT + t) * HDIM;
        Qr[dst + d] = f2b(u1 * c - u2 * s);
        Qr[dst + d + 64] = f2b(u1 * s + u2 * c);
    } else if (bid < 20480) {                // RoPE K -> (B,KVH,T,HD)
        int idx = (bid - 16384) * 256 + threadIdx.x;
        int d = idx & 63;
        int t = (idx >> 6) & (TT - 1);
        int bk = idx >> 16;
        long src = ((long)((bk >> 2) * TT + t)) * 3072 + 2048 + (bk & 3) * HDIM;
        float u1 = b2f(QKVraw[src + d]), u2 = b2f(QKVraw[src + d + 64]);
        float c = b2f(cs[t * 64 + d]), s = b2f(sn[t * 64 + d]);
        long dst = ((long)bk * TT + t) * HDIM;
        Kr[dst + d] = f2b(u1 * c - u2 * s);
        Kr[dst + d + 64] = f2b(u1 * s + u2 * c);
    } else {                                 // V -> (B,KVH,HD,T)
        int idx = (bid - 20480) * 256 + threadIdx.x;
        int t = idx & (TT - 1);
        int d = (idx >> 10) & (HDIM - 1);
        int bk = idx >> 17;
        Vt[idx] = QKVraw[((long)(bk >> 2) * TT + t) * 3072 + 2560 + (bk & 3) * HDIM + d];
    }
}

// ---------------------------------------------------------------------------
// Flash attention v4 — R4 structure (S^T + Ps LDS transport, x32 MFMAs)
// with Q fragments hoisted to registers so the Q LDS buffer is eliminated:
// LDS 59KB -> 43.6KB => 3 blocks/CU (was 2). Q stages through Ks once
// (per-wave rows only -> no barrier, just vmcnt/lgkm waits).
// ---------------------------------------------------------------------------
__global__ __launch_bounds__(256) void attn_kernel(const u16* __restrict__ Q,
                                                   const u16* __restrict__ Kr,
                                                   const u16* __restrict__ Vt,
                                                   u16* __restrict__ O) {
    __shared__ alignas(16) u16 Ks[64 * 128];   // [t][d], 8-chunk ^= row&7 (keep bit3)
    __shared__ alignas(16) u16 Vts[128 * 64];  // [d][t], chunk ^= row&7
    __shared__ alignas(16) u16 Ps[64 * 88];    // [q][k], stride 44 dwords

    const int tid = threadIdx.x, w = tid >> 6, lane = tid & 63;
    const int l16 = lane & 15, quad = lane >> 4;
    const int bid = blockIdx.x;
    const int qt = 15 - (bid & 15);          // heavy tiles first
    const int bh = bid >> 4;
    const int b = bh >> 4, h = bh & 15;
    const int kvh = h >> 2;
    const long qrow0 = (long)bh * TT + qt * 64;
    const long krow0 = (long)(b * NKV + kvh) * TT;
    const long vbase = ((long)(b * NKV + kvh) * HDIM) * TT;

    // Stage this wave's 16 Q rows through the Ks region (own rows only).
#pragma unroll
    for (int i = 0; i < 4; i++) {
        int slot0 = (w * 4 + i) * 64;
        int slot = slot0 + lane;
        int row = slot >> 4, cp = slot & 15;
        int cg = (cp & 8) | ((cp ^ row) & 7);
        async16(Q + (qrow0 + row) * HDIM + cg * 8, &Ks[slot0 * 8]);
    }
    asm volatile("s_waitcnt vmcnt(0)" ::: "memory");
    bf16x8 qf[4];
    {
        const int Rq = w * 16 + l16;
#pragma unroll
        for (int ds = 0; ds < 4; ds++) {
            int c = ds * 4 + quad;
            qf[ds] = *(const bf16x8*)&Ks[Rq * 128 + ((c & 8) | ((c ^ Rq) & 7)) * 8];
        }
    }
    asm volatile("s_waitcnt lgkmcnt(0)" ::: "memory");  // frags in regs before K overwrites

    f32x4 o[8];
#pragma unroll
    for (int i = 0; i < 8; i++) o[i] = {0.f, 0.f, 0.f, 0.f};
    float m_i = -1.0e30f, l_i = 0.f;
    const int qg = qt * 64 + w * 16 + l16;
    const float scale2 = 0.08838834764831845f * 1.4426950408889634f; // 1/sqrt(128)*log2e

    for (int kt = 0; kt <= qt; kt++) {
        __syncthreads();
#pragma unroll
        for (int i = 0; i < 4; i++) {
            int slot0 = (w * 4 + i) * 64;
            int slot = slot0 + lane;
            int row = slot >> 4, cp = slot & 15;
            int cg = (cp & 8) | ((cp ^ row) & 7);
            async16(Kr + (krow0 + kt * 64 + row) * HDIM + cg * 8, &Ks[slot0 * 8]);
        }
#pragma unroll
        for (int i = 0; i < 4; i++) {
            int slot0 = (w * 4 + i) * 64;
            int slot = slot0 + lane;
            int row = slot >> 3, cp = slot & 7;
            int cg = cp ^ (row & 7);
            async16(Vt + vbase + (long)row * TT + kt * 64 + cg * 8, &Vts[slot0 * 8]);
        }
        __syncthreads();

        // S^T[k][q] = sum_d K[k][d] * Q[q][d]  (Q from registers)
        f32x4 s[4];
#pragma unroll
        for (int nt = 0; nt < 4; nt++) s[nt] = {0.f, 0.f, 0.f, 0.f};
#pragma unroll
        for (int ds = 0; ds < 4; ds++) {
            int c = ds * 4 + quad;
#pragma unroll
            for (int nt = 0; nt < 4; nt++) {
                int Rk = nt * 16 + l16;
                bf16x8 ak = *(const bf16x8*)&Ks[Rk * 128 + ((c & 8) | ((c ^ Rk) & 7)) * 8];
                s[nt] = __builtin_amdgcn_mfma_f32_16x16x32_bf16(ak, qf[ds], s[nt], 0, 0, 0);
            }
        }

        // online softmax (exp2 domain)
        float p[4][4];
        float mx = -1.0e30f;
        if (kt == qt) {
#pragma unroll
            for (int nt = 0; nt < 4; nt++)
#pragma unroll
                for (int r = 0; r < 4; r++) {
                    int kcol = kt * 64 + nt * 16 + quad * 4 + r;
                    float v = (kcol <= qg) ? (float)s[nt][r] * scale2 : -1.0e30f;
                    p[nt][r] = v;
                    mx = fmaxf(mx, v);
                }
        } else {
#pragma unroll
            for (int nt = 0; nt < 4; nt++)
#pragma unroll
                for (int r = 0; r < 4; r++) {
                    float v = (float)s[nt][r] * scale2;
                    p[nt][r] = v;
                    mx = fmaxf(mx, v);
                }
        }
        mx = fmaxf(mx, __shfl_xor(mx, 16));
        mx = fmaxf(mx, __shfl_xor(mx, 32));
        float mnew = fmaxf(m_i, mx);
        float alpha = exp2f(m_i - mnew);
        float rs = 0.f;
#pragma unroll
        for (int nt = 0; nt < 4; nt++)
#pragma unroll
            for (int r = 0; r < 4; r++) {
                float e = exp2f(p[nt][r] - mnew);
                p[nt][r] = e;
                rs += e;
            }
        rs += __shfl_xor(rs, 16);
        rs += __shfl_xor(rs, 32);
        l_i = l_i * alpha + rs;

        // P -> Ps (packed u32, own-wave rows)
        u32* Psw = (u32*)Ps;
        int pb = (w * 16 + l16) * 44 + quad * 2;
#pragma unroll
        for (int nt = 0; nt < 4; nt++) {
            u32 lo = (u32)f2b(p[nt][0]) | ((u32)f2b(p[nt][1]) << 16);
            u32 hi = (u32)f2b(p[nt][2]) | ((u32)f2b(p[nt][3]) << 16);
            Psw[pb + nt * 8]     = lo;
            Psw[pb + nt * 8 + 1] = hi;
        }
        // rescale O only if some lane's max moved (wave-uniform branch)
        if (__ballot(mnew != m_i) != 0ULL) {
#pragma unroll
            for (int n8 = 0; n8 < 8; n8++)
#pragma unroll
                for (int r = 0; r < 4; r++) o[n8][r] *= alpha;
        }
        m_i = mnew;

        asm volatile("s_waitcnt lgkmcnt(0)" ::: "memory");  // Ps W->R, same wave

        // O^T[d][q] += V^T[d][k] * P[q][k]
#pragma unroll
        for (int ks = 0; ks < 2; ks++) {
            bf16x8 bp = *(const bf16x8*)&Ps[(w * 16 + l16) * 88 + ks * 32 + quad * 8];
#pragma unroll
            for (int n8 = 0; n8 < 8; n8++) {
                int Rv = n8 * 16 + l16;
                int c = ks * 4 + quad;
                bf16x8 av = *(const bf16x8*)&Vts[Rv * 64 + (c ^ (Rv & 7)) * 8];
                o[n8] = __builtin_amdgcn_mfma_f32_16x16x32_bf16(av, bp, o[n8], 0, 0, 0);
            }
        }
    }

    // epilogue: normalize, pack, store
    float inv = 1.0f / l_i;
    long obase = ((long)(b * TT + qg)) * CDIM + h * HDIM;
#pragma unroll
    for (int n8 = 0; n8 < 8; n8++) {
        ushort4 st;
        st.x = f2b(o[n8][0] * inv);
        st.y = f2b(o[n8][1] * inv);
        st.z = f2b(o[n8][2] * inv);
        st.w = f2b(o[n8][3] * inv);
        *(ushort4*)&O[obase + n8 * 16 + quad * 4] = st;
    }
}

// ---------------------------------------------------------------------------
extern "C" void kernel_launch(void* const* d_in, const int* in_sizes, int n_in,
                              void* d_out, int out_size, void* d_ws, size_t ws_size,
                              hipStream_t stream) {
    const void* x   = d_in[0];
    const void* Wq  = d_in[1];
    const void* Wkv = d_in[2];
    const void* Wo  = d_in[3];
    const void* cs  = d_in[4];
    const void* sn  = d_in[5];

    char* ws = (char*)d_ws;
    const size_t NEED = 105119748;
    if (ws_size < NEED) return;

    u16* WqkvT = (u16*)(ws + 0);          // 3072x2048 (WqT ++ WkvT)
    u16* WoT   = (u16*)(ws + 12582912);   // 2048x2048
    u16* QKVraw= (u16*)(ws + 20971520);   // 4096x3072
    u16* Qr    = (u16*)(ws + 46137344);   // (B,H,T,HD)
    u16* Kr    = (u16*)(ws + 62914560);   // (B,KVH,T,HD)
    u16* Vt    = (u16*)(ws + 67108864);   // (B,KVH,HD,T)
    u16* ATT   = (u16*)(ws + 71303168);   // 4096x2048
    u16* xb    = (u16*)(ws + 88080384);   // 4096x2048 bf16 x
    u16* csb   = (u16*)(ws + 104857600);  // 1024x64
    u16* snb   = (u16*)(ws + 104988672);  // 1024x64
    u32* flag  = (u32*)(ws + 105119744);

    detect_k<<<1, 256, 0, stream>>>((const u16*)x, flag);

    conv_k<<<8192, 256, 0, stream>>>(x, xb, flag, 8388608);
    conv2_k<<<128, 256, 0, stream>>>(cs, sn, csb, snb, flag);

    transpose_all_k<<<2560, 256, 0, stream>>>(Wq, Wkv, Wo, WqkvT, WoT, flag);

    gemm_bt<<<dim3(24, 32), 256, 0, stream>>>(xb, WqkvT, QKVraw, 4096, 3072, 2048, nullptr);

    prep_k<<<28672, 256, 0, stream>>>(QKVraw, csb, snb, Qr, Kr, Vt);

    attn_kernel<<<1024, 256, 0, stream>>>(Qr, Kr, Vt, ATT);

    gemm_bt<<<dim3(16, 32), 256, 0, stream>>>(ATT, WoT, d_out, 4096, 2048, 2048, flag);
}

// Round 7
// 328.146 us; speedup vs baseline: 1.3616x; 1.1028x over previous
//
#include <hip/hip_runtime.h>

typedef unsigned short u16;
typedef unsigned int u32;
typedef __bf16 bf16x8 __attribute__((ext_vector_type(8)));
typedef float f32x4 __attribute__((ext_vector_type(4)));

#define BB   4
#define TT   1024
#define CDIM 2048
#define NH   16
#define NKV  4
#define HDIM 128

__device__ __forceinline__ float b2f(u16 u) {
    union { u32 i; float f; } x; x.i = ((u32)u) << 16; return x.f;
}
__device__ __forceinline__ u16 f2b(float f) {
    union { float f; u32 i; } x; x.f = f;
    u32 r = (x.i + 0x7fffu + ((x.i >> 16) & 1u)) >> 16;
    return (u16)r;
}
__device__ __forceinline__ void async16(const void* g, void* l) {
    __builtin_amdgcn_global_load_lds((const __attribute__((address_space(1))) void*)g,
                                     (__attribute__((address_space(3))) void*)l, 16, 0, 0);
}

// Inline dtype probe: every wave samples the same 64 even u16s of x (low
// mantissa halves if fp32 -> uniform-random exponents -> ~72% implausible;
// real bf16 N(0,1) -> ~0%). Ballot => identical wave-uniform verdict everywhere.
__device__ __forceinline__ bool wave_is_f32(const u16* xp) {
    u16 v = xp[(threadIdx.x & 63) * 2];
    int e = (v >> 7) & 0xFF;
    bool bad = (v != 0) && (e < 90 || e > 160);
    return __popcll(__ballot(bad)) > 16;
}

// ---------------------------------------------------------------------------
// Fused pre-pass: convert x, cos, sin to bf16 + all three weight transposes.
// Block ranges: [0,8192) x | [8192,8256) cos | [8256,8320) sin | [8320,10880) W.
// ---------------------------------------------------------------------------
__global__ __launch_bounds__(256) void pre_k(const void* __restrict__ x,
                                             const void* __restrict__ Wq,
                                             const void* __restrict__ Wkv,
                                             const void* __restrict__ Wo,
                                             u16* __restrict__ xb,
                                             u16* __restrict__ csb,
                                             u16* __restrict__ snb,
                                             u16* __restrict__ WqkvT,
                                             u16* __restrict__ WoT,
                                             const void* __restrict__ cs,
                                             const void* __restrict__ sn) {
    const bool f32m = wave_is_f32((const u16*)x);
    int bid = blockIdx.x;
    if (bid < 8320) {                        // element-wise conversions
        const void* src; u16* dst; int i;
        if (bid < 8192)      { src = x;  dst = xb;  i = bid * 256 + threadIdx.x; }
        else if (bid < 8256) { src = cs; dst = csb; i = (bid - 8192) * 256 + threadIdx.x; }
        else                 { src = sn; dst = snb; i = (bid - 8256) * 256 + threadIdx.x; }
        union { u16 u[4]; ushort4 v; } o;
        if (f32m) {
            float4 f = ((const float4*)src)[i];
            o.u[0] = f2b(f.x); o.u[1] = f2b(f.y); o.u[2] = f2b(f.z); o.u[3] = f2b(f.w);
        } else {
            o.v = ((const ushort4*)src)[i];
        }
        ((ushort4*)dst)[i] = o.v;
        return;
    }
    // weight transpose: WT[c][r] = bf16(W[r][c])
    __shared__ alignas(16) u16 tile[64 * 65];
    int t = bid - 8320;
    const void* W; u16* WT; int rows, cols, bx, by;
    if (t < 1024)      { W = Wq;  WT = WqkvT;                    rows = 2048; cols = 2048; bx = t & 31;  by = t >> 5; }
    else if (t < 1536) { int l = t - 1024; W = Wkv; WT = WqkvT + (long)2048 * 2048; rows = 2048; cols = 1024; bx = l & 15; by = l >> 4; }
    else               { int l = t - 1536; W = Wo;  WT = WoT;  rows = 2048; cols = 2048; bx = l & 31;   by = l >> 5; }
    const int r0 = by * 64, c0 = bx * 64;
#pragma unroll
    for (int i = 0; i < 16; i++) {
        int c = threadIdx.x + i * 256;
        int rr = c >> 6, cc = c & 63;
        long idx = (long)(r0 + rr) * cols + c0 + cc;
        tile[rr * 65 + cc] = f32m ? f2b(((const float*)W)[idx]) : ((const u16*)W)[idx];
    }
    __syncthreads();
#pragma unroll
    for (int i = 0; i < 16; i++) {
        int c = threadIdx.x + i * 256;
        int rr = c >> 6, cc = c & 63;
        WT[(long)(c0 + rr) * rows + r0 + cc] = tile[cc * 65 + rr];
    }
}

// ---------------------------------------------------------------------------
// m97-style bf16 GEMM: C[m][n] = sum_k A[m][k] * Bt[n][k].
// Output fp32 iff xprobe non-null and detects fp32 inputs.
// ---------------------------------------------------------------------------
__global__ __launch_bounds__(256) void gemm_bt(const u16* __restrict__ A,
                                               const u16* __restrict__ Bt,
                                               void* __restrict__ C,
                                               int M, int N, int Kd,
                                               const u16* __restrict__ xprobe) {
    __shared__ alignas(16) u16 As[128 * 32];
    __shared__ alignas(16) u16 Bs[128 * 32];
    const bool f32m = (xprobe != nullptr) && wave_is_f32(xprobe);
    const int tid = threadIdx.x;
    const int w = tid >> 6, lane = tid & 63;
    const int wm = w >> 1, wn = w & 1;
    const int l16 = lane & 15, quad = lane >> 4;
    const int bm = blockIdx.y, bn = blockIdx.x;
    const long arow0 = (long)bm * 128;
    const long brow0 = (long)bn * 128;
    const int srow = lane >> 2;
    const int schunk = lane & 3;

    f32x4 acc[4][4];
#pragma unroll
    for (int i = 0; i < 4; i++)
#pragma unroll
        for (int j = 0; j < 4; j++) acc[i][j] = {0.f, 0.f, 0.f, 0.f};

    for (int k0 = 0; k0 < Kd; k0 += 32) {
        __syncthreads();
#pragma unroll
        for (int j = 0; j < 2; j++) {
            int r0 = w * 32 + j * 16;
            const u16* gA = A + (arow0 + r0 + srow) * Kd + k0 + schunk * 8;
            async16(gA, &As[r0 * 32]);
            const u16* gB = Bt + (brow0 + r0 + srow) * Kd + k0 + schunk * 8;
            async16(gB, &Bs[r0 * 32]);
        }
        __syncthreads();
        bf16x8 af[4], bfr[4];
#pragma unroll
        for (int mt = 0; mt < 4; mt++)
            af[mt] = *(const bf16x8*)&As[(wm * 64 + mt * 16 + l16) * 32 + quad * 8];
#pragma unroll
        for (int nt = 0; nt < 4; nt++)
            bfr[nt] = *(const bf16x8*)&Bs[(wn * 64 + nt * 16 + l16) * 32 + quad * 8];
#pragma unroll
        for (int mt = 0; mt < 4; mt++)
#pragma unroll
            for (int nt = 0; nt < 4; nt++)
                acc[mt][nt] = __builtin_amdgcn_mfma_f32_16x16x32_bf16(
                    af[mt], bfr[nt], acc[mt][nt], 0, 0, 0);
    }
#pragma unroll
    for (int mt = 0; mt < 4; mt++) {
#pragma unroll
        for (int nt = 0; nt < 4; nt++) {
            int col = bn * 128 + wn * 64 + nt * 16 + l16;
#pragma unroll
            for (int r = 0; r < 4; r++) {
                long row = bm * 128 + wm * 64 + mt * 16 + quad * 4 + r;
                if (f32m) ((float*)C)[row * N + col] = acc[mt][nt][r];
                else      ((u16*)C)[row * N + col] = f2b(acc[mt][nt][r]);
            }
        }
    }
}

// ---------------------------------------------------------------------------
// RoPE(Q), RoPE(K), V-transpose in one dispatch, split by block ranges.
// ---------------------------------------------------------------------------
__global__ __launch_bounds__(256) void prep_k(const u16* __restrict__ QKVraw,
                                              const u16* __restrict__ cs,
                                              const u16* __restrict__ sn,
                                              u16* __restrict__ Qr,
                                              u16* __restrict__ Kr,
                                              u16* __restrict__ Vt) {
    int bid = blockIdx.x;
    if (bid < 16384) {                       // RoPE Q -> (B,H,T,HD)
        int idx = bid * 256 + threadIdx.x;
        int d = idx & 63;
        int t = (idx >> 6) & (TT - 1);
        int bh = idx >> 16;
        long src = ((long)((bh >> 4) * TT + t)) * 3072 + (bh & 15) * HDIM;
        float u1 = b2f(QKVraw[src + d]), u2 = b2f(QKVraw[src + d + 64]);
        float c = b2f(cs[t * 64 + d]), s = b2f(sn[t * 64 + d]);
        long dst = ((long)bh * TT + t) * HDIM;
        Qr[dst + d] = f2b(u1 * c - u2 * s);
        Qr[dst + d + 64] = f2b(u1 * s + u2 * c);
    } else if (bid < 20480) {                // RoPE K -> (B,KVH,T,HD)
        int idx = (bid - 16384) * 256 + threadIdx.x;
        int d = idx & 63;
        int t = (idx >> 6) & (TT - 1);
        int bk = idx >> 16;
        long src = ((long)((bk >> 2) * TT + t)) * 3072 + 2048 + (bk & 3) * HDIM;
        float u1 = b2f(QKVraw[src + d]), u2 = b2f(QKVraw[src + d + 64]);
        float c = b2f(cs[t * 64 + d]), s = b2f(sn[t * 64 + d]);
        long dst = ((long)bk * TT + t) * HDIM;
        Kr[dst + d] = f2b(u1 * c - u2 * s);
        Kr[dst + d + 64] = f2b(u1 * s + u2 * c);
    } else {                                 // V -> (B,KVH,HD,T)
        int idx = (bid - 20480) * 256 + threadIdx.x;
        int t = idx & (TT - 1);
        int d = (idx >> 10) & (HDIM - 1);
        int bk = idx >> 17;
        Vt[idx] = QKVraw[((long)(bk >> 2) * TT + t) * 3072 + 2560 + (bk & 3) * HDIM + d];
    }
}

// ---------------------------------------------------------------------------
// Flash attention v5: balanced persistent pairs + double-buffered K/V with
// fine-grained vmcnt (loads stay in flight across compute; vmcnt(0) never
// runs inside the K-loop). 1024 items (bh, qt) sorted heavy-first; block b
// does items {b, 1023-b} => exactly 17 tile-iterations per block; grid 512
// = 2 blocks/CU resident (LDS 75KB). Compute per tile identical to R4/R6
// (verified): S^T = K·Q^T, in-lane online softmax, Ps LDS hop, O^T = V^T·P^T.
// ---------------------------------------------------------------------------
__global__ __launch_bounds__(256) void attn_kernel(const u16* __restrict__ Q,
                                                   const u16* __restrict__ Kr,
                                                   const u16* __restrict__ Vt,
                                                   u16* __restrict__ O) {
    __shared__ alignas(16) u16 Ks[2][64 * 128];   // [t][d], chunk ^= row&7 (bit3 kept)
    __shared__ alignas(16) u16 Vts[2][128 * 64];  // [d][t], chunk ^= row&7
    __shared__ alignas(16) u16 Ps[64 * 88];       // [q][k], per-wave rows only

    const int tid = threadIdx.x, w = tid >> 6, lane = tid & 63;
    const int l16 = lane & 15, quad = lane >> 4;
    const float scale2 = 0.08838834764831845f * 1.4426950408889634f; // 1/sqrt(128)*log2e

#pragma unroll 1
    for (int it = 0; it < 2; it++) {
        const int j = it ? (1023 - (int)blockIdx.x) : (int)blockIdx.x;
        const int qt = 15 - (j >> 6);        // heavy first for it==0
        const int bh = j & 63;
        const int b = bh >> 4, h = bh & 15;
        const int kvh = h >> 2;
        const long qrow0 = (long)bh * TT + qt * 64;
        const long krow0 = (long)(b * NKV + kvh) * TT;
        const long vbase = ((long)(b * NKV + kvh) * HDIM) * TT;

        __syncthreads();  // prior item's LDS reads done; full drain

        // ---- stage this wave's 16 Q rows through Ks[0] (own slots only) ----
#pragma unroll
        for (int i = 0; i < 4; i++) {
            int slot0 = (w * 4 + i) * 64;
            int slot = slot0 + lane;
            int row = slot >> 4, cp = slot & 15;
            int cg = (cp & 8) | ((cp ^ row) & 7);
            async16(Q + (qrow0 + row) * HDIM + cg * 8, &Ks[0][slot0 * 8]);
        }
        asm volatile("s_waitcnt vmcnt(0)" ::: "memory");
        bf16x8 qf[4];
        {
            const int Rq = w * 16 + l16;
#pragma unroll
            for (int ds = 0; ds < 4; ds++) {
                int c = ds * 4 + quad;
                qf[ds] = *(const bf16x8*)&Ks[0][Rq * 128 + ((c & 8) | ((c ^ Rq) & 7)) * 8];
            }
        }
        asm volatile("s_waitcnt lgkmcnt(0)" ::: "memory");  // frags in regs

        // ---- prologue staging: tile0 -> buf0 (overwrites Q, own slots), tile1 -> buf1
#pragma unroll
        for (int i = 0; i < 4; i++) {
            int slot0 = (w * 4 + i) * 64;
            int slot = slot0 + lane;
            int row = slot >> 4, cp = slot & 15;
            int cg = (cp & 8) | ((cp ^ row) & 7);
            async16(Kr + (krow0 + row) * HDIM + cg * 8, &Ks[0][slot0 * 8]);
        }
#pragma unroll
        for (int i = 0; i < 4; i++) {
            int slot0 = (w * 4 + i) * 64;
            int slot = slot0 + lane;
            int row = slot >> 3, cp = slot & 7;
            int cg = cp ^ (row & 7);
            async16(Vt + vbase + (long)row * TT + cg * 8, &Vts[0][slot0 * 8]);
        }
        if (qt >= 1) {
#pragma unroll
            for (int i = 0; i < 4; i++) {
                int slot0 = (w * 4 + i) * 64;
                int slot = slot0 + lane;
                int row = slot >> 4, cp = slot & 15;
                int cg = (cp & 8) | ((cp ^ row) & 7);
                async16(Kr + (krow0 + 64 + row) * HDIM + cg * 8, &Ks[1][slot0 * 8]);
            }
#pragma unroll
            for (int i = 0; i < 4; i++) {
                int slot0 = (w * 4 + i) * 64;
                int slot = slot0 + lane;
                int row = slot >> 3, cp = slot & 7;
                int cg = cp ^ (row & 7);
                async16(Vt + vbase + (long)row * TT + 64 + cg * 8, &Vts[1][slot0 * 8]);
            }
            asm volatile("s_waitcnt vmcnt(8)" ::: "memory");  // tile0 done, tile1 in flight
        } else {
            asm volatile("s_waitcnt vmcnt(0)" ::: "memory");
        }
        asm volatile("s_barrier" ::: "memory");

        f32x4 o[8];
#pragma unroll
        for (int i = 0; i < 8; i++) o[i] = {0.f, 0.f, 0.f, 0.f};
        float m_i = -1.0e30f, l_i = 0.f;
        const int qg = qt * 64 + w * 16 + l16;

#pragma unroll 1
        for (int kt = 0; kt <= qt; kt++) {
            const int cur = kt & 1;
            const u16* ksb = Ks[cur];
            const u16* vsb = Vts[cur];

            // S^T[k][q] = sum_d K[k][d] * Q[q][d]
            f32x4 s[4];
#pragma unroll
            for (int nt = 0; nt < 4; nt++) s[nt] = {0.f, 0.f, 0.f, 0.f};
#pragma unroll
            for (int ds = 0; ds < 4; ds++) {
                int c = ds * 4 + quad;
#pragma unroll
                for (int nt = 0; nt < 4; nt++) {
                    int Rk = nt * 16 + l16;
                    bf16x8 ak = *(const bf16x8*)&ksb[Rk * 128 + ((c & 8) | ((c ^ Rk) & 7)) * 8];
                    s[nt] = __builtin_amdgcn_mfma_f32_16x16x32_bf16(ak, qf[ds], s[nt], 0, 0, 0);
                }
            }

            // online softmax (exp2 domain), in-lane 16 values + 2 shuffles
            float p[4][4];
            float mx = -1.0e30f;
            if (kt == qt) {
#pragma unroll
                for (int nt = 0; nt < 4; nt++)
#pragma unroll
                    for (int r = 0; r < 4; r++) {
                        int kcol = kt * 64 + nt * 16 + quad * 4 + r;
                        float v = (kcol <= qg) ? (float)s[nt][r] * scale2 : -1.0e30f;
                        p[nt][r] = v;
                        mx = fmaxf(mx, v);
                    }
            } else {
#pragma unroll
                for (int nt = 0; nt < 4; nt++)
#pragma unroll
                    for (int r = 0; r < 4; r++) {
                        float v = (float)s[nt][r] * scale2;
                        p[nt][r] = v;
                        mx = fmaxf(mx, v);
                    }
            }
            mx = fmaxf(mx, __shfl_xor(mx, 16));
            mx = fmaxf(mx, __shfl_xor(mx, 32));
            float mnew = fmaxf(m_i, mx);
            float alpha = exp2f(m_i - mnew);
            float rs = 0.f;
#pragma unroll
            for (int nt = 0; nt < 4; nt++)
#pragma unroll
                for (int r = 0; r < 4; r++) {
                    float e = exp2f(p[nt][r] - mnew);
                    p[nt][r] = e;
                    rs += e;
                }
            rs += __shfl_xor(rs, 16);
            rs += __shfl_xor(rs, 32);
            l_i = l_i * alpha + rs;

            // P -> Ps (packed u32, own-wave rows)
            u32* Psw = (u32*)Ps;
            int pb = (w * 16 + l16) * 44 + quad * 2;
#pragma unroll
            for (int nt = 0; nt < 4; nt++) {
                u32 lo = (u32)f2b(p[nt][0]) | ((u32)f2b(p[nt][1]) << 16);
                u32 hi = (u32)f2b(p[nt][2]) | ((u32)f2b(p[nt][3]) << 16);
                Psw[pb + nt * 8]     = lo;
                Psw[pb + nt * 8 + 1] = hi;
            }
            if (__ballot(mnew != m_i) != 0ULL) {
#pragma unroll
                for (int n8 = 0; n8 < 8; n8++)
#pragma unroll
                    for (int r = 0; r < 4; r++) o[n8][r] *= alpha;
            }
            m_i = mnew;

            asm volatile("s_waitcnt lgkmcnt(0)" ::: "memory");  // Ps W->R, same wave

            // O^T[d][q] += V^T[d][k] * P[q][k]
#pragma unroll
            for (int ks = 0; ks < 2; ks++) {
                bf16x8 bp = *(const bf16x8*)&Ps[(w * 16 + l16) * 88 + ks * 32 + quad * 8];
#pragma unroll
                for (int n8 = 0; n8 < 8; n8++) {
                    int Rv = n8 * 16 + l16;
                    int c = ks * 4 + quad;
                    bf16x8 av = *(const bf16x8*)&vsb[Rv * 64 + (c ^ (Rv & 7)) * 8];
                    o[n8] = __builtin_amdgcn_mfma_f32_16x16x32_bf16(av, bp, o[n8], 0, 0, 0);
                }
            }

            if (kt == qt) break;

            // pipeline maintenance: reads of buf[cur] done -> refill it with kt+2
            asm volatile("s_waitcnt lgkmcnt(0)" ::: "memory");  // own ds_reads complete
            asm volatile("s_barrier" ::: "memory");             // all waves done with buf[cur]
            if (kt + 2 <= qt) {
                const int nk = kt + 2;
#pragma unroll
                for (int i = 0; i < 4; i++) {
                    int slot0 = (w * 4 + i) * 64;
                    int slot = slot0 + lane;
                    int row = slot >> 4, cp = slot & 15;
                    int cg = (cp & 8) | ((cp ^ row) & 7);
                    async16(Kr + (krow0 + nk * 64 + row) * HDIM + cg * 8, &Ks[cur][slot0 * 8]);
                }
#pragma unroll
                for (int i = 0; i < 4; i++) {
                    int slot0 = (w * 4 + i) * 64;
                    int slot = slot0 + lane;
                    int row = slot >> 3, cp = slot & 7;
                    int cg = cp ^ (row & 7);
                    async16(Vt + vbase + (long)row * TT + nk * 64 + cg * 8, &Vts[cur][slot0 * 8]);
                }
                asm volatile("s_waitcnt vmcnt(8)" ::: "memory");  // (kt+1)'s loads done
            } else {
                asm volatile("s_waitcnt vmcnt(0)" ::: "memory");
            }
            asm volatile("s_barrier" ::: "memory");  // buf[1-cur] ready across waves
        }

        // epilogue: normalize, pack, store this item's 64 q-rows
        float inv = 1.0f / l_i;
        long obase = ((long)(b * TT + qg)) * CDIM + h * HDIM;
#pragma unroll
        for (int n8 = 0; n8 < 8; n8++) {
            ushort4 st;
            st.x = f2b(o[n8][0] * inv);
            st.y = f2b(o[n8][1] * inv);
            st.z = f2b(o[n8][2] * inv);
            st.w = f2b(o[n8][3] * inv);
            *(ushort4*)&O[obase + n8 * 16 + quad * 4] = st;
        }
    }
}

// ---------------------------------------------------------------------------
extern "C" void kernel_launch(void* const* d_in, const int* in_sizes, int n_in,
                              void* d_out, int out_size, void* d_ws, size_t ws_size,
                              hipStream_t stream) {
    const void* x   = d_in[0];
    const void* Wq  = d_in[1];
    const void* Wkv = d_in[2];
    const void* Wo  = d_in[3];
    const void* cs  = d_in[4];
    const void* sn  = d_in[5];

    char* ws = (char*)d_ws;
    const size_t NEED = 105119748;
    if (ws_size < NEED) return;

    u16* WqkvT = (u16*)(ws + 0);          // 3072x2048 (WqT ++ WkvT)
    u16* WoT   = (u16*)(ws + 12582912);   // 2048x2048
    u16* QKVraw= (u16*)(ws + 20971520);   // 4096x3072
    u16* Qr    = (u16*)(ws + 46137344);   // (B,H,T,HD)
    u16* Kr    = (u16*)(ws + 62914560);   // (B,KVH,T,HD)
    u16* Vt    = (u16*)(ws + 67108864);   // (B,KVH,HD,T)
    u16* ATT   = (u16*)(ws + 71303168);   // 4096x2048
    u16* xb    = (u16*)(ws + 88080384);   // 4096x2048 bf16 x
    u16* csb   = (u16*)(ws + 104857600);  // 1024x64
    u16* snb   = (u16*)(ws + 104988672);  // 1024x64

    pre_k<<<10880, 256, 0, stream>>>(x, Wq, Wkv, Wo, xb, csb, snb, WqkvT, WoT, cs, sn);

    gemm_bt<<<dim3(24, 32), 256, 0, stream>>>(xb, WqkvT, QKVraw, 4096, 3072, 2048, nullptr);

    prep_k<<<28672, 256, 0, stream>>>(QKVraw, csb, snb, Qr, Kr, Vt);

    attn_kernel<<<512, 256, 0, stream>>>(Qr, Kr, Vt, ATT);

    gemm_bt<<<dim3(16, 32), 256, 0, stream>>>(ATT, WoT, d_out, 4096, 2048, 2048, (const u16*)x);
}